// Round 7
// baseline (213.511 us; speedup 1.0000x reference)
//
#include <hip/hip_runtime.h>
#include <hip/hip_bf16.h>
#include <cstdint>
#include <cstddef>

typedef __bf16 bf16;
typedef __bf16 bf16x4 __attribute__((ext_vector_type(4)));
typedef __bf16 bf16x8 __attribute__((ext_vector_type(8)));
typedef float f32x4 __attribute__((ext_vector_type(4)));

#define LOG2E 1.4426950408889634f
#define QSCALE (0.03125f * LOG2E)   // C^-0.5 * log2(e), folded into Q
#define PSHIFT 8.0f                 // fixed softmax shift, folded into QK acc init

#define GLD16(gp, lp)                                                              \
  __builtin_amdgcn_global_load_lds((__attribute__((address_space(1))) void*)(gp),  \
                                   (__attribute__((address_space(3))) void*)(lp),  \
                                   16, 0, 0)

// ---------------- fused prep: x->bf16 + W_qkv^T + W_out^T (one launch) ----------------
__global__ void k_prep(const float* __restrict__ x, const float* __restrict__ Wqkv,
                       const float* __restrict__ Wout, bf16* __restrict__ xb,
                       bf16* __restrict__ wqT, bf16* __restrict__ woT) {
  const int blk = blockIdx.x, tid = threadIdx.x;
  if (blk < 2048) {
    int i = (blk * 256 + tid) * 8;
    const float4* p = (const float4*)(x + i);
    float4 a = p[0], b = p[1];
    bf16x8 o;
    o[0] = (bf16)a.x; o[1] = (bf16)a.y; o[2] = (bf16)a.z; o[3] = (bf16)a.w;
    o[4] = (bf16)b.x; o[5] = (bf16)b.y; o[6] = (bf16)b.z; o[7] = (bf16)b.w;
    *(bf16x8*)(xb + i) = o;
    return;
  }
  const float* in;
  bf16* out;
  int R = 1024, C, bx, by;
  if (blk < 2048 + 3072) {
    in = Wqkv; out = wqT; C = 3072;
    bx = (blk - 2048) % 96; by = (blk - 2048) / 96;
  } else {
    in = Wout; out = woT; C = 1024;
    bx = (blk - 5120) % 32; by = (blk - 5120) / 32;
  }
  __shared__ float t[32][33];
  const int tx = tid & 31, ty = tid >> 5;
  int c0 = bx * 32, r0 = by * 32;
#pragma unroll
  for (int i = 0; i < 4; i++)
    t[ty + i * 8][tx] = in[(size_t)(r0 + ty + i * 8) * C + c0 + tx];
  __syncthreads();
#pragma unroll
  for (int i = 0; i < 4; i++)
    out[(size_t)(c0 + ty + i * 8) * R + r0 + tx] = (bf16)t[tx][ty + i * 8];
}

// ---------------- GEMM: C = A[M,1024] @ Bt[N,1024]^T, BK=64 ----------------
template <int EPI>
__global__ __launch_bounds__(256, 2) void k_gemm_bt(
    const bf16* __restrict__ A, const bf16* __restrict__ Bt,
    const float* __restrict__ bias, float* __restrict__ outF,
    bf16* __restrict__ qb, bf16* __restrict__ kb, bf16* __restrict__ vb) {
  __shared__ __align__(16) bf16 As[128 * 64];  // 16B-block XOR (row&7)
  __shared__ __align__(16) bf16 Bs[128 * 64];
  const int tid = threadIdx.x;
  const int lane = tid & 63, w = tid >> 6;
  const int quad = lane >> 4, l16 = lane & 15;
  const int wm = (w >> 1) * 64, wn = (w & 1) * 64;
  const int bm = blockIdx.y * 128, bn = blockIdx.x * 128;
  f32x4 acc[4][4] = {};

  for (int kt = 0; kt < 1024; kt += 64) {
    __syncthreads();
#pragma unroll
    for (int p = 0; p < 4; p++) {
      int idx = p * 256 + tid;
      int row = idx >> 3, bq = idx & 7;
      int gb = bq ^ (row & 7);  // logical block gb stored at position bq
      GLD16(A + (size_t)(bm + row) * 1024 + kt + gb * 8, As + idx * 8);
      GLD16(Bt + (size_t)(bn + row) * 1024 + kt + gb * 8, Bs + idx * 8);
    }
    __syncthreads();

#pragma unroll
    for (int s = 0; s < 2; s++) {  // K=32 sub-steps
      bf16x8 af[4], bfr[4];
#pragma unroll
      for (int mi = 0; mi < 4; mi++) {
        int row = wm + mi * 16 + l16;
        af[mi] = *(const bf16x8*)(As + row * 64 + (((s * 4 + quad) ^ (row & 7)) << 3));
      }
#pragma unroll
      for (int ni = 0; ni < 4; ni++) {
        int row = wn + ni * 16 + l16;
        bfr[ni] = *(const bf16x8*)(Bs + row * 64 + (((s * 4 + quad) ^ (row & 7)) << 3));
      }
#pragma unroll
      for (int mi = 0; mi < 4; mi++)
#pragma unroll
        for (int ni = 0; ni < 4; ni++)
          acc[mi][ni] =
              __builtin_amdgcn_mfma_f32_16x16x32_bf16(af[mi], bfr[ni], acc[mi][ni], 0, 0, 0);
    }
  }

#pragma unroll
  for (int ni = 0; ni < 4; ni++) {
    int col = bn + wn + ni * 16 + l16;
    float bv = bias[col];
    if (EPI == 1) {
#pragma unroll
      for (int mi = 0; mi < 4; mi++)
#pragma unroll
        for (int r = 0; r < 4; r++) {
          int row = bm + wm + mi * 16 + quad * 4 + r;
          outF[(size_t)row * 1024 + col] = acc[mi][ni][r] + bv;
        }
    } else {
      int which = col >> 10, cc = col & 1023;
      int h = cc >> 6, d = cc & 63;
      if (which == 2) {
#pragma unroll
        for (int mi = 0; mi < 4; mi++) {
          int rowb = bm + wm + mi * 16 + quad * 4;
          int b = rowb >> 11, n0 = rowb & 2047;
          bf16x4 vv;
#pragma unroll
          for (int r = 0; r < 4; r++) vv[r] = (bf16)(acc[mi][ni][r] + bv);
          *(bf16x4*)(vb + ((size_t)(b * 16 + h) * 64 + d) * 2048 + n0) = vv;
        }
      } else {
#pragma unroll
        for (int mi = 0; mi < 4; mi++)
#pragma unroll
          for (int r = 0; r < 4; r++) {
            int row = bm + wm + mi * 16 + quad * 4 + r;
            int b = row >> 11, n = row & 2047;
            float v = acc[mi][ni][r] + bv;
            if (which == 0)
              qb[((size_t)(b * 16 + h) * 2048 + n) * 64 + d] = (bf16)(v * QSCALE);
            else
              kb[((size_t)(b * 16 + h) * 2048 + n) * 64 + d] = (bf16)v;
          }
      }
    }
  }
}

// ---------------- flash attention: (kw,qw) 2x2 wave split, 16x16x32 only ----------------
// grid (qb=32, bh=32); 64 q x 64 key per iter, 32 iters, dbuf K/V.
// Wave (kw=w&1, qw=w>>1): QK for keys [kw*32,+32) x q [qw*32,+32); P to shared
// Ps[qw]; barrier; PV for quadrant d in [kw*32,+32) x q [qw*32,+32) over all 64
// keys. Each wave owns a disjoint O quadrant -> no cross-wave O reduction; lsum
// reduced via 512B Ls. LDS 42.5 KB -> 3 blocks/CU.
__global__ __launch_bounds__(256, 3) void k_flash(
    const bf16* __restrict__ Q, const bf16* __restrict__ K,
    const bf16* __restrict__ V, bf16* __restrict__ O) {
  __shared__ __align__(16) bf16 Kt[2][64 * 64];  // [key][d], 16B-block XOR (key&7)
  __shared__ __align__(16) bf16 Vt[2][64 * 64];  // [d][key], 16B-block XOR (d&7)
  __shared__ __align__(16) bf16 Ps[2][32 * 72];  // [qw][q32][key64], stride 72 (16B-mult)
  __shared__ float Ls[64][2];                    // [q][kw] lsum partials
  const int tid = threadIdx.x;
  const int lane = tid & 63, w = tid >> 6;
  const int quad = lane >> 4, l16 = lane & 15;
  const int kw = w & 1, qw = w >> 1;
  const int bh = blockIdx.y, qb = blockIdx.x;
  const bf16* qh = Q + (size_t)bh * 2048 * 64;
  const bf16* kh = K + (size_t)bh * 2048 * 64;
  const bf16* vh = V + (size_t)bh * 64 * 2048;

  // Q frags (B of S^T): n = q = qw*32 + qt*16 + l16, k = d = kc*32 + quad*8 + j
  bf16x8 qf[2][2];
#pragma unroll
  for (int qt = 0; qt < 2; qt++)
#pragma unroll
    for (int kc = 0; kc < 2; kc++)
      qf[qt][kc] = *(const bf16x8*)(qh + (size_t)(qb * 64 + qw * 32 + qt * 16 + l16) * 64 +
                                    kc * 32 + quad * 8);

  f32x4 o[2][2] = {};  // [dnj][qt]: row d = kw*32+dnj*16+quad*4+r, col q = qw*32+qt*16+l16
  float lp[2] = {0.f, 0.f};

  bf16* ps = &Ps[qw][0];

  auto stage = [&](int kt, int buf) {
#pragma unroll
    for (int p = 0; p < 2; p++) {
      int idx = p * 256 + tid;
      int row = idx >> 3, bq = idx & 7, gb = bq ^ (row & 7);
      GLD16(kh + (size_t)(kt * 64 + row) * 64 + gb * 8, &Kt[buf][idx * 8]);
      GLD16(vh + (size_t)row * 2048 + kt * 64 + gb * 8, &Vt[buf][idx * 8]);
    }
  };

  stage(0, 0);

  for (int kt = 0; kt < 32; kt++) {
    const int p = kt & 1;
    __syncthreads();  // [A] buf[p] ready; prior PV reads of Ps done; buf[p^1] free
    if (kt < 31) stage(kt + 1, p ^ 1);
    const bf16* Kb = &Kt[p][0];
    const bf16* Vb = &Vt[p][0];

    // S^T = K_w · Q^T (wave's 32 keys x 32 q); acc init -PSHIFT
    f32x4 s[2][2];  // [knj][qt]
#pragma unroll
    for (int knj = 0; knj < 2; knj++) {
      int krow = kw * 32 + knj * 16 + l16;
      bf16x8 kf0 = *(const bf16x8*)(Kb + krow * 64 + ((quad ^ (krow & 7)) << 3));
      bf16x8 kf1 = *(const bf16x8*)(Kb + krow * 64 + (((4 + quad) ^ (krow & 7)) << 3));
#pragma unroll
      for (int qt = 0; qt < 2; qt++) {
        f32x4 t = {-PSHIFT, -PSHIFT, -PSHIFT, -PSHIFT};
        t = __builtin_amdgcn_mfma_f32_16x16x32_bf16(kf0, qf[qt][0], t, 0, 0, 0);
        t = __builtin_amdgcn_mfma_f32_16x16x32_bf16(kf1, qf[qt][1], t, 0, 0, 0);
        s[knj][qt] = t;
      }
    }

    // P = exp2(s); per-lane lsum partials; pack into Ps[qw][q][key]
#pragma unroll
    for (int knj = 0; knj < 2; knj++)
#pragma unroll
      for (int qt = 0; qt < 2; qt++) {
        float p0 = __builtin_amdgcn_exp2f(s[knj][qt][0]);
        float p1 = __builtin_amdgcn_exp2f(s[knj][qt][1]);
        float p2 = __builtin_amdgcn_exp2f(s[knj][qt][2]);
        float p3 = __builtin_amdgcn_exp2f(s[knj][qt][3]);
        lp[qt] += (p0 + p1) + (p2 + p3);
        bf16x4 pk = {(bf16)p0, (bf16)p1, (bf16)p2, (bf16)p3};
        // key = kw*32 + knj*16 + quad*4 + r; q-row = qt*16 + l16
        *(bf16x4*)(ps + (qt * 16 + l16) * 72 + kw * 32 + knj * 16 + quad * 4) = pk;
      }

    __syncthreads();  // [B] P published across kw-siblings

    // O^T quadrant += V^T[d in kw-half][all 64 keys] · P^T[all keys][q in qw-half]
#pragma unroll
    for (int kc = 0; kc < 2; kc++) {
      bf16x8 pf[2];
#pragma unroll
      for (int qt = 0; qt < 2; qt++)
        pf[qt] = *(const bf16x8*)(ps + (qt * 16 + l16) * 72 + kc * 32 + quad * 8);
#pragma unroll
      for (int dnj = 0; dnj < 2; dnj++) {
        int drow = kw * 32 + dnj * 16 + l16;
        bf16x8 vf = *(const bf16x8*)(Vb + drow * 64 + (((kc * 4 + quad) ^ (drow & 7)) << 3));
        o[dnj][0] = __builtin_amdgcn_mfma_f32_16x16x32_bf16(vf, pf[0], o[dnj][0], 0, 0, 0);
        o[dnj][1] = __builtin_amdgcn_mfma_f32_16x16x32_bf16(vf, pf[1], o[dnj][1], 0, 0, 0);
      }
    }
  }

  // epilogue: reduce lsum over quads, then over kw via Ls; write own quadrant
#pragma unroll
  for (int qt = 0; qt < 2; qt++) {
    lp[qt] += __shfl_xor(lp[qt], 16, 64);
    lp[qt] += __shfl_xor(lp[qt], 32, 64);
  }
  if (lane < 16) {
    Ls[qw * 32 + lane][kw] = lp[0];
    Ls[qw * 32 + 16 + lane][kw] = lp[1];
  }
  __syncthreads();
  const int b = bh >> 4, h = bh & 15;
#pragma unroll
  for (int qt = 0; qt < 2; qt++) {
    int q = qw * 32 + qt * 16 + l16;
    float inv = 1.0f / (Ls[q][0] + Ls[q][1]);
    int n = qb * 64 + q;
#pragma unroll
    for (int dnj = 0; dnj < 2; dnj++) {
      bf16x4 ov;
#pragma unroll
      for (int r = 0; r < 4; r++) ov[r] = (bf16)(o[dnj][qt][r] * inv);
      int c = h * 64 + kw * 32 + dnj * 16 + quad * 4;
      *(bf16x4*)(O + ((size_t)b * 2048 + n) * 1024 + c) = ov;
    }
  }
}

// ---------------- launch ----------------

extern "C" void kernel_launch(void* const* d_in, const int* in_sizes, int n_in,
                              void* d_out, int out_size, void* d_ws, size_t ws_size,
                              hipStream_t stream) {
  (void)in_sizes; (void)n_in; (void)out_size; (void)ws_size;
  const float* x    = (const float*)d_in[0];
  const float* Wqkv = (const float*)d_in[1];
  const float* bqkv = (const float*)d_in[2];
  const float* Wout = (const float*)d_in[3];
  const float* bout = (const float*)d_in[4];
  float* out = (float*)d_out;

  char* ws = (char*)d_ws;
  size_t off = 0;
  auto take = [&](size_t bytes) {
    char* p = ws + off;
    off += (bytes + 255) & ~(size_t)255;
    return p;
  };
  bf16* xb   = (bf16*)take((size_t)4096 * 1024 * 2);
  bf16* wqT  = (bf16*)take((size_t)3072 * 1024 * 2);
  bf16* woT  = (bf16*)take((size_t)1024 * 1024 * 2);
  bf16* qbuf = (bf16*)take((size_t)32 * 2048 * 64 * 2);
  bf16* kbuf = (bf16*)take((size_t)32 * 2048 * 64 * 2);
  bf16* vbuf = (bf16*)take((size_t)32 * 2048 * 64 * 2);
  bf16* aout = (bf16*)take((size_t)4096 * 1024 * 2);

  k_prep<<<6144, 256, 0, stream>>>(x, Wqkv, Wout, xb, wqT, woT);
  k_gemm_bt<0><<<dim3(24, 32), 256, 0, stream>>>(xb, wqT, bqkv, nullptr, qbuf, kbuf, vbuf);
  k_flash<<<dim3(32, 32), 256, 0, stream>>>(qbuf, kbuf, vbuf, aout);
  k_gemm_bt<1><<<dim3(8, 32), 256, 0, stream>>>(aout, woT, bout, out, nullptr, nullptr, nullptr);
}